// Round 6
// baseline (175.973 us; speedup 1.0000x reference)
//
#include <hip/hip_runtime.h>

#define NB 65536
#define D 64
#define SLOPE 0.2f

typedef _Float16 h2f __attribute__((ext_vector_type(2)));

__device__ __forceinline__ h2f as_h2(unsigned x) {
    union { unsigned u; h2f h; } v; v.u = x; return v.h;
}
__device__ __forceinline__ float fdot2w(unsigned w, h2f u, float acc) {
#if __has_builtin(__builtin_amdgcn_fdot2)
    return __builtin_amdgcn_fdot2(as_h2(w), u, acc, false);
#else
    h2f e = as_h2(w);
    return acc + (float)e.x * (float)u.x + (float)e.y * (float)u.y;
#endif
}

__device__ __forceinline__ float reduce8(float v) {
#pragma unroll
    for (int off = 1; off <= 4; off <<= 1)
        v += __shfl_xor(v, off, 64);
    return v;
}
__device__ __forceinline__ float reduce64(float v) {
#pragma unroll
    for (int off = 1; off <= 32; off <<= 1)
        v += __shfl_xor(v, off, 64);
    return v;
}

__device__ __forceinline__ int lower_bound(const int* __restrict__ seg, int n, int key) {
    int lo = 0, hi = n;
    while (lo < hi) {
        int mid = (lo + hi) >> 1;
        if (seg[mid] < key) lo = mid + 1;
        else hi = mid;
    }
    return lo;
}

// ---------------- pre-pass: quarter-split f16 table + segment offsets ----------------
// qtab layout: quarter q (dims 16q..16q+15) -> qtab_u32[q*NE*8 + id*8 + slot], slot=pair of dims
__global__ __launch_bounds__(256)
void prepass(const float2* __restrict__ ef2, unsigned* __restrict__ qtab, int n2, int NE,
             const int* __restrict__ a_seg, int Ta, int* __restrict__ offs_a,
             const int* __restrict__ c_seg, int Tc, int* __restrict__ offs_c)
{
    const int t = blockIdx.x * blockDim.x + threadIdx.x;
    if (t < n2) {
        float2 v = ef2[t];
        const int elem = t * 2;
        const int id = elem >> 6;         // / D
        const int d  = elem & 63;
        const int q  = d >> 4;
        const int w  = (d & 15) >> 1;     // u32 slot 0..7 within quarter row
        h2f h = { (_Float16)v.x, (_Float16)v.y };
        union { h2f h; unsigned u; } cv; cv.h = h;
        qtab[(size_t)q * NE * 8 + id * 8 + w] = cv.u;
    }
    if (t < Ta) {
        int s = a_seg[t];
        if (t == 0) offs_a[0] = 0;
        else if (a_seg[t - 1] != s) offs_a[s] = t;
        if (t == Ta - 1) offs_a[s + 1] = Ta;
    }
    if (t < Tc) {
        int s = c_seg[t];
        if (t == 0) offs_c[0] = 0;
        else if (c_seg[t - 1] != s) offs_c[s] = t;
        if (t == Tc - 1) offs_c[s + 1] = Tc;
    }
}

// ---------------- phase-gather: wave = (quarter q, row b); quarter is SLOW index ----------------
__global__ __launch_bounds__(256)
void gather_q(const int* __restrict__ user_id,
              const int* __restrict__ a_ids, const int* __restrict__ offs_a,
              const int* __restrict__ c_ids, const int* __restrict__ offs_c,
              const float* __restrict__ uf,
              const unsigned* __restrict__ qtab, int NE,
              float* __restrict__ part)     // part[(q*2+aspect)*NB + b]
{
    const int wid  = blockIdx.x * 4 + (threadIdx.x >> 6);
    const int lane = threadIdx.x & 63;
    const int q = wid >> 16;          // 0..3 (slow -> phases time-separated)
    const int b = wid & 0xFFFF;
    const int rg = lane >> 2;         // row subgroup 0..15
    const int c4 = lane & 3;          // dim chunk 0..3 (4 dims = 1 uint2)

    const int uid = user_id[b];
    const float4 uq = reinterpret_cast<const float4*>(uf)[uid * 16 + q * 4 + c4];
    const h2f uh0 = { (_Float16)uq.x, (_Float16)uq.y };
    const h2f uh1 = { (_Float16)uq.z, (_Float16)uq.w };

    const uint2* __restrict__ qt =
        reinterpret_cast<const uint2*>(qtab + (size_t)q * NE * 8);

    auto gath = [&](const int* __restrict__ ids, int s, int e) -> float {
        float acc = 0.f;
        int t = s;
        for (; t + 32 <= e; t += 32) {
            const int i0 = ids[t + rg];
            const int i1 = ids[t + 16 + rg];
            const uint2 w0 = qt[i0 * 4 + c4];
            const uint2 w1 = qt[i1 * 4 + c4];
            acc = fdot2w(w0.x, uh0, acc);
            acc = fdot2w(w0.y, uh1, acc);
            acc = fdot2w(w1.x, uh0, acc);
            acc = fdot2w(w1.y, uh1, acc);
        }
        if (t + rg < e) {
            const uint2 w0 = qt[ids[t + rg] * 4 + c4];
            acc = fdot2w(w0.x, uh0, acc);
            acc = fdot2w(w0.y, uh1, acc);
        }
        t += 16;
        if (t + rg < e) {
            const uint2 w1 = qt[ids[t + rg] * 4 + c4];
            acc = fdot2w(w1.x, uh0, acc);
            acc = fdot2w(w1.y, uh1, acc);
        }
        return reduce64(acc);
    };

    const float pa = gath(a_ids, offs_a[b], offs_a[b + 1]);
    const float pc = gath(c_ids, offs_c[b], offs_c[b + 1]);
    if (lane == 0) {
        part[(q * 2 + 0) * NB + b] = pa;
        part[(q * 2 + 1) * NB + b] = pc;
    }
}

// ---------------- final: softmax + combine + outputs ----------------
__global__ __launch_bounds__(256)
void final_k(const int* __restrict__ user_id,
             const int* __restrict__ offs_a, const int* __restrict__ offs_c,
             const float* __restrict__ uf, const float* __restrict__ relation_k,
             const float* __restrict__ part, float* __restrict__ out)
{
    const int b    = blockIdx.x * 4 + (threadIdx.x >> 6);
    const int lane = threadIdx.x & 63;
    const int c = lane & 7;

    const int uid = user_id[b];
    const float4 ua = reinterpret_cast<const float4*>(uf)[uid * 16 + 2 * c];
    const float4 ub = reinterpret_cast<const float4*>(uf)[uid * 16 + 2 * c + 1];

    float p0 = 0.f, p1 = 0.f, p2 = 0.f;
    {
        const float uv[8] = {ua.x, ua.y, ua.z, ua.w, ub.x, ub.y, ub.z, ub.w};
#pragma unroll
        for (int j = 0; j < 8; ++j) {
            const int row = 8 * c + j;
            p0 += uv[j] * relation_k[row * 3 + 0];
            p1 += uv[j] * relation_k[row * 3 + 1];
            p2 += uv[j] * relation_k[row * 3 + 2];
        }
    }
    float l0 = reduce8(p0), l1 = reduce8(p1), l2 = reduce8(p2);
    l0 = l0 > 0.f ? l0 : SLOPE * l0;
    l1 = l1 > 0.f ? l1 : SLOPE * l1;
    l2 = l2 > 0.f ? l2 : SLOPE * l2;
    const float m  = fmaxf(l0, fmaxf(l1, l2));
    const float e0 = __expf(l0 - m);
    const float e1 = __expf(l1 - m);
    const float e2 = __expf(l2 - m);
    const float inv = 1.0f / (e0 + e1 + e2);
    const float s0 = e0 * inv, s1 = e1 * inv, s2 = e2 * inv;

    // quarter partials: slot = q*2 + aspect, lanes 0..7 load in parallel
    const float pv = (lane < 8) ? part[lane * NB + b] : 0.f;
    const float c_a_sum = __shfl(pv, 0, 64) + __shfl(pv, 2, 64) +
                          __shfl(pv, 4, 64) + __shfl(pv, 6, 64);
    const float c_c_sum = __shfl(pv, 1, 64) + __shfl(pv, 3, 64) +
                          __shfl(pv, 5, 64) + __shfl(pv, 7, 64);
    const float na = (float)(offs_a[b + 1] - offs_a[b]);
    const float nc = (float)(offs_c[b + 1] - offs_c[b]);
    const float c_a = c_a_sum / na;
    const float c_c = c_c_sum / nc;

    const float pred = (c_a * s0 + c_c * s1) / (s0 + s1);

    if (lane == 0) {
        out[b]          = pred;
        out[4 * NB + b] = c_a;
        out[5 * NB + b] = c_c;
    }
    if (lane < 3) {
        const float sv = (lane == 0) ? s0 : ((lane == 1) ? s1 : s2);
        out[NB + 3 * b + lane] = sv;
    }
}

// ---------------- fallback (no workspace): bsearch + fp32, correctness only ----------------
__global__ __launch_bounds__(256)
void aspect_fallback(const int* __restrict__ user_id,
                     const int* __restrict__ a_ids, const int* __restrict__ a_seg, int Ta,
                     const int* __restrict__ c_ids, const int* __restrict__ c_seg, int Tc,
                     const float* __restrict__ user_factors,
                     const float4* __restrict__ ef4,
                     const float* __restrict__ relation_k,
                     float* __restrict__ out)
{
    const int b    = blockIdx.x * 4 + (threadIdx.x >> 6);
    const int lane = threadIdx.x & 63;
    const int g = lane >> 4, k = lane & 15;

    const int uid = user_id[b];
    const float4 u4 = reinterpret_cast<const float4*>(user_factors)[uid * 16 + k];

    float p0 = 0.f, p1 = 0.f, p2 = 0.f;
    {
        const float uv[4] = {u4.x, u4.y, u4.z, u4.w};
#pragma unroll
        for (int j = 0; j < 4; ++j) {
            const int row = 4 * k + j;
            p0 += uv[j] * relation_k[row * 3 + 0];
            p1 += uv[j] * relation_k[row * 3 + 1];
            p2 += uv[j] * relation_k[row * 3 + 2];
        }
    }
    // reduce over 16 k-lanes
#pragma unroll
    for (int off = 1; off <= 8; off <<= 1) {
        p0 += __shfl_xor(p0, off, 64);
        p1 += __shfl_xor(p1, off, 64);
        p2 += __shfl_xor(p2, off, 64);
    }
    float l0 = p0 > 0.f ? p0 : SLOPE * p0;
    float l1 = p1 > 0.f ? p1 : SLOPE * p1;
    float l2 = p2 > 0.f ? p2 : SLOPE * p2;
    const float m  = fmaxf(l0, fmaxf(l1, l2));
    const float e0 = __expf(l0 - m), e1 = __expf(l1 - m), e2 = __expf(l2 - m);
    const float inv = 1.0f / (e0 + e1 + e2);
    const float s0 = e0 * inv, s1 = e1 * inv, s2 = e2 * inv;

    auto gd = [&](const int* __restrict__ ids, int s, int e) -> float {
        float ax = 0.f, ay = 0.f, az = 0.f, aw = 0.f;
        int t = s;
        for (; t + 4 <= e; t += 4) {
            const float4 v0 = ef4[ids[t + g] * 16 + k];
            ax += v0.x; ay += v0.y; az += v0.z; aw += v0.w;
        }
        if (t + g < e) {
            const float4 v0 = ef4[ids[t + g] * 16 + k];
            ax += v0.x; ay += v0.y; az += v0.z; aw += v0.w;
        }
        return reduce64(ax * u4.x + ay * u4.y + az * u4.z + aw * u4.w);
    };

    const int sa = lower_bound(a_seg, Ta, b), ea = lower_bound(a_seg, Ta, b + 1);
    const int sc = lower_bound(c_seg, Tc, b), ec = lower_bound(c_seg, Tc, b + 1);
    const float c_a = gd(a_ids, sa, ea) / (float)(ea - sa);
    const float c_c = gd(c_ids, sc, ec) / (float)(ec - sc);
    const float pred = (c_a * s0 + c_c * s1) / (s0 + s1);

    if (lane == 0) {
        out[b]          = pred;
        out[4 * NB + b] = c_a;
        out[5 * NB + b] = c_c;
    }
    if (lane < 3) {
        const float sv = (lane == 0) ? s0 : ((lane == 1) ? s1 : s2);
        out[NB + 3 * b + lane] = sv;
    }
}

extern "C" void kernel_launch(void* const* d_in, const int* in_sizes, int n_in,
                              void* d_out, int out_size, void* d_ws, size_t ws_size,
                              hipStream_t stream) {
    const int*   user_id        = (const int*)d_in[0];
    const int*   artists_ids    = (const int*)d_in[1];
    const int*   artists_seg    = (const int*)d_in[2];
    const int*   categories_ids = (const int*)d_in[3];
    const int*   categories_seg = (const int*)d_in[4];
    const float* user_factors   = (const float*)d_in[5];
    const float* entity_factors = (const float*)d_in[6];
    const float* relation_k     = (const float*)d_in[7];
    float* out = (float*)d_out;

    const int Ta = in_sizes[1];
    const int Tc = in_sizes[3];
    const int n_ent_elems = in_sizes[6];      // N_ENTITY * D
    const int NE = n_ent_elems / D;
    const int n2 = n_ent_elems / 2;

    const size_t offs_bytes = (size_t)2 * (NB + 1) * sizeof(int);
    const size_t part_bytes = (size_t)8 * NB * sizeof(float);
    const size_t qtab_bytes = (size_t)n_ent_elems * 2;    // 4 quarters x NE x 16 f16

    if (ws_size >= offs_bytes + part_bytes + qtab_bytes) {
        int*      offs_a = (int*)d_ws;
        int*      offs_c = offs_a + (NB + 1);
        float*    part   = (float*)((unsigned char*)d_ws + offs_bytes);
        unsigned* qtab   = (unsigned*)((unsigned char*)d_ws + offs_bytes + part_bytes);

        int prep_n = n2 > Ta ? n2 : Ta;
        if (Tc > prep_n) prep_n = Tc;
        prepass<<<(prep_n + 255) / 256, 256, 0, stream>>>(
            (const float2*)entity_factors, qtab, n2, NE,
            artists_seg, Ta, offs_a,
            categories_seg, Tc, offs_c);

        // 4 quarters x NB rows, quarter = slow blockIdx index
        gather_q<<<NB, 256, 0, stream>>>(user_id,
            artists_ids, offs_a, categories_ids, offs_c,
            user_factors, qtab, NE, part);

        final_k<<<NB / 4, 256, 0, stream>>>(user_id, offs_a, offs_c,
            user_factors, relation_k, part, out);
    } else {
        aspect_fallback<<<NB / 4, 256, 0, stream>>>(user_id,
            artists_ids, artists_seg, Ta,
            categories_ids, categories_seg, Tc,
            user_factors, (const float4*)entity_factors, relation_k, out);
    }
}